// Round 7
// baseline (354.561 us; speedup 1.0000x reference)
//
#include <hip/hip_runtime.h>
#include <stdint.h>

#define BDIM 2048
#define KDIM 768
#define NTOT 16140
#define NKT 24   // 768 / 32

typedef _Float16 half8 __attribute__((ext_vector_type(8)));
typedef float floatx4 __attribute__((ext_vector_type(4)));

__device__ __forceinline__ unsigned short f2h(float f) {
  _Float16 h = (_Float16)f;   // RNE, matches original prep conversion bit-exactly
  return __builtin_bit_cast(unsigned short, h);
}

__device__ __forceinline__ void level_of(int col, int& cb, int& Cl, long long& ob) {
  if      (col < 20)   { cb = 0;    Cl = 20;    ob = 0LL; }
  else if (col < 90)   { cb = 20;   Cl = 70;    ob = 40960LL; }
  else if (col < 340)  { cb = 90;   Cl = 250;   ob = 184320LL; }
  else if (col < 1140) { cb = 340;  Cl = 800;   ob = 696320LL; }
  else if (col < 4140) { cb = 1140; Cl = 3000;  ob = 2334720LL; }
  else                 { cb = 4140; Cl = 12000; ob = 8478720LL; }
}

// direct global->LDS async copy, 16B per lane; lds dst = uniform base + lane*16
__device__ __forceinline__ void gload_lds16(const void* g, void* l) {
  __builtin_amdgcn_global_load_lds(
      (const __attribute__((address_space(1))) unsigned int*)g,
      (__attribute__((address_space(3))) unsigned int*)l, 16, 0, 0);
}

// ---------------- tiny prep: convert x fp32->fp16 + gst table + concatenated bias ----------------
// items: [0, 393216) x float4 convert; [393216, +4142) gst; then 16140 bcat -> 413498 total
__global__ __launch_bounds__(256) void prep_kernel(
    const float* __restrict__ x,
    const float* __restrict__ b0, const float* __restrict__ b1, const float* __restrict__ b2,
    const float* __restrict__ b3, const float* __restrict__ b4, const float* __restrict__ b5,
    const int* __restrict__ p1, const int* __restrict__ p2, const int* __restrict__ p3,
    const int* __restrict__ p4, const int* __restrict__ p5,
    unsigned short* __restrict__ xh, int* __restrict__ gst, float* __restrict__ bcat)
{
  long long gtid = (long long)blockIdx.x * 256 + threadIdx.x;
  if (gtid < 393216LL) {   // x: 2048*768/4 float4
    float4 v = reinterpret_cast<const float4*>(x)[gtid];
    ushort4 o;
    o.x = f2h(v.x); o.y = f2h(v.y); o.z = f2h(v.z); o.w = f2h(v.w);
    reinterpret_cast<ushort4*>(xh)[gtid] = o;
    return;
  }
  long long u = gtid - 393216LL;
  if (u < 4142) {
    // gst[j]: child-range start of global parent j in concatenated col space.
    // ids: 0=root; [1,21)=L0; [21,91)=L1; [91,341)=L2; [341,1141)=L3; [1141,4141)=L4.
    int j = (int)u;
    int val;
    if (j == 0) val = 0;
    else if (j == 4141) val = 16140;
    else {
      const int* p; int C, s, base;
      if      (j < 21)   { p = p1; C = 70;    s = j - 1;    base = 20; }
      else if (j < 91)   { p = p2; C = 250;   s = j - 21;   base = 90; }
      else if (j < 341)  { p = p3; C = 800;   s = j - 91;   base = 340; }
      else if (j < 1141) { p = p4; C = 3000;  s = j - 341;  base = 1140; }
      else               { p = p5; C = 12000; s = j - 1141; base = 4140; }
      int lo = 0, hi = C;
      while (lo < hi) { int mid = (lo + hi) >> 1; if (p[mid] < s) lo = mid + 1; else hi = mid; }
      val = base + lo;
    }
    gst[j] = val;
    return;
  }
  long long v5 = u - 4142;
  if (v5 < 16140) {
    int col = (int)v5;
    int cb, Cl; long long ob; level_of(col, cb, Cl, ob);
    const float* bs;
    if      (col < 20)   bs = b0;
    else if (col < 90)   bs = b1;
    else if (col < 340)  bs = b2;
    else if (col < 1140) bs = b3;
    else if (col < 4140) bs = b4;
    else                 bs = b5;
    bcat[col] = bs[col - cb];
  }
}

// ---------------- fp16 MFMA GEMM: logits = x @ Wcat^T, W converted in-flight ----------------
// A (x fp16): global_load_lds width-16 double-buffered (m97 path).
// B (W fp32): reg-staged — global fp32 -> regs -> RNE cvt -> ds_write_b128, same LDS layout.
//   Kills the 74 MB W-conversion pass; fp32 W col-tiles are L2-resident per XCD (swizzle).
#define EPI_STRIDE 132 // floats per staged C row (132 mod 32 = 4 -> conflict-free)

__global__ __launch_bounds__(256, 2) void gemm_kernel(
    const unsigned short* __restrict__ Ah,   // [2048][768] fp16
    const float* __restrict__ Wf0, const float* __restrict__ Wf1,
    const float* __restrict__ Wf2, const float* __restrict__ Wf3,
    const float* __restrict__ Wf4, const float* __restrict__ Wf5,
    float* __restrict__ out)
{
  __shared__ __align__(16) char smem_raw[64 * EPI_STRIDE * 4];  // 33792 B; staging uses 32768
  float* epi = (float*)smem_raw;

  // XCD-aware swizzle (2032 = 8*254, bijective)
  const int bid = blockIdx.x;
  const int logical = (bid & 7) * 254 + (bid >> 3);
  const int cx = logical >> 4;                // col tile 0..126
  const int row0 = (logical & 15) * 128;
  const int col0 = cx * 128;

  const int tid  = threadIdx.x;
  const int wave = tid >> 6;
  const int lane = tid & 63;
  const int wr = (wave >> 1) * 64;
  const int wc = (wave & 1) * 64;
  const int q  = lane >> 4;
  const int lr = lane & 15;

  const int rquad = lane >> 2;
  const int kq = lane & 3;

  floatx4 acc[4][4];
#pragma unroll
  for (int i = 0; i < 4; ++i)
#pragma unroll
    for (int j = 0; j < 4; ++j)
      acc[i][j] = (floatx4){0.f, 0.f, 0.f, 0.f};

  // ---- A staging (fp16, global_load_lds): per wave 2 chunks of 16 rows ----
  const unsigned short* gA[2];
#pragma unroll
  for (int i = 0; i < 2; ++i) {
    int c = 2 * wave + i;
    int rowA = row0 + 16 * c + rquad;
    gA[i] = Ah + (long long)rowA * KDIM + kq * 8;
  }
  auto stageA = [&](int buf, int kt) {
#pragma unroll
    for (int i = 0; i < 2; ++i) {
      int c = 2 * wave + i;
      gload_lds16(gA[i] + kt * 32, smem_raw + buf * 8192 + c * 1024);
    }
  };

  // ---- B staging (fp32 W, reg path): slot s in [0,512): LDS halfs [s*8, s*8+8)
  //      = row (s>>2) of B tile, k-offset (s&3)*8; thread t owns slots t, t+256. ----
  const float* gBs[2];
#pragma unroll
  for (int i = 0; i < 2; ++i) {
    int s = tid + i * 256;
    int colB = col0 + (s >> 2);
    if (colB >= NTOT) colB = NTOT - 1;
    int cb, Cl; long long ob; level_of(colB, cb, Cl, ob);
    const float* Wp;
    if      (colB < 20)   Wp = Wf0;
    else if (colB < 90)   Wp = Wf1;
    else if (colB < 340)  Wp = Wf2;
    else if (colB < 1140) Wp = Wf3;
    else if (colB < 4140) Wp = Wf4;
    else                  Wp = Wf5;
    gBs[i] = Wp + (long long)(colB - cb) * KDIM + (s & 3) * 8;
  }

  float4 rb[2][2];
  auto loadB = [&](int kt) {
    const int kb = kt * 32;
#pragma unroll
    for (int i = 0; i < 2; ++i) {
      rb[i][0] = *reinterpret_cast<const float4*>(gBs[i] + kb);
      rb[i][1] = *reinterpret_cast<const float4*>(gBs[i] + kb + 4);
    }
  };
  auto writeB = [&](int buf) {
#pragma unroll
    for (int i = 0; i < 2; ++i) {
      int s = tid + i * 256;
      union { ushort u[8]; uint4 v; } pk;
      pk.u[0] = f2h(rb[i][0].x); pk.u[1] = f2h(rb[i][0].y);
      pk.u[2] = f2h(rb[i][0].z); pk.u[3] = f2h(rb[i][0].w);
      pk.u[4] = f2h(rb[i][1].x); pk.u[5] = f2h(rb[i][1].y);
      pk.u[6] = f2h(rb[i][1].z); pk.u[7] = f2h(rb[i][1].w);
      *reinterpret_cast<uint4*>(smem_raw + 16384 + buf * 8192 + s * 16) = pk.v;
    }
  };

  // ---- prologue: fill buf0 (A async + B reg), preload B regs for kt=1 ----
  stageA(0, 0);
  loadB(0);
  writeB(0);          // compiler inserts vmcnt wait for loadB(0) before cvt use
  loadB(1);
  __syncthreads();    // drains A(0) gload_lds + B ds_writes

  int cur = 0;
  for (int kt = 0; kt < NKT; ++kt) {
    if (kt + 1 < NKT) {
      stageA(cur ^ 1, kt + 1);   // async global->LDS
      writeB(cur ^ 1);           // B data for kt+1 (regs loaded last iter)
    }
    if (kt + 2 < NKT) loadB(kt + 2);   // in flight through the MFMA phase
    const char* Ac = smem_raw + cur * 8192;
    const char* Bc = smem_raw + 16384 + cur * 8192;
    half8 af[4], bf[4];
#pragma unroll
    for (int i = 0; i < 4; ++i)
      af[i] = __builtin_bit_cast(half8, *(const uint4*)(Ac + (wr + i * 16 + lr) * 64 + q * 16));
#pragma unroll
    for (int j = 0; j < 4; ++j)
      bf[j] = __builtin_bit_cast(half8, *(const uint4*)(Bc + (wc + j * 16 + lr) * 64 + q * 16));
#pragma unroll
    for (int i = 0; i < 4; ++i)
#pragma unroll
      for (int j = 0; j < 4; ++j)
        acc[i][j] = __builtin_amdgcn_mfma_f32_16x16x32_f16(af[i], bf[j], acc[i][j], 0, 0, 0);
    __syncthreads();
    cur ^= 1;
  }

  // ---- epilogue: stage C-tile through LDS, write coalesced float4 rows ----
  int cbA, ClA; long long obA; level_of(col0, cbA, ClA, obA);
  int cbB, ClB; long long obB; level_of(col0 + 127, cbB, ClB, obB);
  const bool fast = (cbA == cbB) && ((cbA & 3) == 0) && ((ClA & 3) == 0) && (col0 + 128 <= NTOT);

  for (int h = 0; h < 2; ++h) {
    __syncthreads();
    if ((wave >> 1) == h) {
#pragma unroll
      for (int i = 0; i < 4; ++i)
#pragma unroll
        for (int j = 0; j < 4; ++j)
#pragma unroll
          for (int rg = 0; rg < 4; ++rg)
            epi[(i * 16 + q * 4 + rg) * EPI_STRIDE + wc + j * 16 + lr] = acc[i][j][rg];
    }
    __syncthreads();
    if (fast) {
      const long long rowbase = obA + (long long)(row0 + h * 64) * ClA + (col0 - cbA);
#pragma unroll
      for (int it = 0; it < 8; ++it) {
        int idx = it * 256 + tid;
        int r = idx >> 5, f4 = idx & 31;
        float4 v = *(const float4*)(epi + r * EPI_STRIDE + f4 * 4);
        *(float4*)(out + rowbase + (long long)r * ClA + f4 * 4) = v;
      }
    } else {
      for (int idx = tid; idx < 64 * 128; idx += 256) {
        int r = idx >> 7, c = idx & 127;
        int col = col0 + c;
        if (col < NTOT) {
          int cb, Cl; long long ob; level_of(col, cb, Cl, ob);
          out[ob + (long long)(row0 + h * 64 + r) * Cl + (col - cb)] = epi[r * EPI_STRIDE + c];
        }
      }
    }
  }
}

// ---------------- fused 6-level tree softmax, one row per block (r3 structure, 1024 thr) ----------------
// p_L[c] = e_L[c] * T[parent(c)],  T[n] = e[n]*T[par(n)]/S[n],  S[n] = sum children e.
__global__ __launch_bounds__(1024) void tree_softmax_kernel(
    float* __restrict__ out,
    const float* __restrict__ bcat, const int* __restrict__ gst,
    const int* __restrict__ p1, const int* __restrict__ p2, const int* __restrict__ p3,
    const int* __restrict__ p4, const int* __restrict__ p5)
{
  __shared__ __align__(16) float l[NTOT];    // e-values, all levels concat
  __shared__ __align__(16) float S[4141];    // seg sums -> T values in place
  const int tid = threadIdx.x;
  const long long row = blockIdx.x;

  // ---- Phase 1: e = exp(logit + bias), one balanced vectorized pass ----
  if (tid < 340) {   // levels 0..2 scalar (20 + 70 + 250)
    float v;
    if      (tid < 20) v = out[row * 20 + tid] + bcat[tid];
    else if (tid < 90) v = out[40960 + row * 70 + (tid - 20)] + bcat[tid];
    else               v = out[184320 + row * 250 + (tid - 90)] + bcat[tid];
    l[tid] = __expf(v);
  }
  if (tid < 200) {   // L3: 800 = 200 float4
    float4 v = reinterpret_cast<const float4*>(out + 696320 + row * 800)[tid];
    float4 b = reinterpret_cast<const float4*>(bcat + 340)[tid];
    float4 e;
    e.x = __expf(v.x + b.x); e.y = __expf(v.y + b.y);
    e.z = __expf(v.z + b.z); e.w = __expf(v.w + b.w);
    reinterpret_cast<float4*>(l + 340)[tid] = e;
  }
  if (tid < 750) {   // L4: 3000 = 750 float4
    float4 v = reinterpret_cast<const float4*>(out + 2334720 + row * 3000)[tid];
    float4 b = reinterpret_cast<const float4*>(bcat + 1140)[tid];
    float4 e;
    e.x = __expf(v.x + b.x); e.y = __expf(v.y + b.y);
    e.z = __expf(v.z + b.z); e.w = __expf(v.w + b.w);
    reinterpret_cast<float4*>(l + 1140)[tid] = e;
  }
  for (int i4 = tid; i4 < 3000; i4 += 1024) { // L5: 12000 = 3000 float4
    float4 v = reinterpret_cast<const float4*>(out + 8478720 + row * 12000)[i4];
    float4 b = reinterpret_cast<const float4*>(bcat + 4140)[i4];
    float4 e;
    e.x = __expf(v.x + b.x); e.y = __expf(v.y + b.y);
    e.z = __expf(v.z + b.z); e.w = __expf(v.w + b.w);
    reinterpret_cast<float4*>(l + 4140)[i4] = e;
  }
  __syncthreads();

  // ---- Phase 2: all segment sums, one balanced pass (no atomics) ----
  for (int j = tid; j < 4141; j += 1024) {
    int a = gst[j], b = gst[j + 1];
    float s = 0.f;
    for (int c = a; c < b; ++c) s += l[c];
    S[j] = s;   // empty segment -> 0 -> T=inf, never gathered
  }
  __syncthreads();

  // ---- Phase 3: T-chain in place over S ----
  if (tid < 20) {            // root + L0 nodes (single wave: S[0] read-before-write safe)
    float s0 = S[0];
    float inv = 1.f / s0;
    float t = l[tid] * inv / S[1 + tid];
    S[1 + tid] = t;
    if (tid == 0) S[0] = inv;
  }
  __syncthreads();
  if (tid < 70)
    S[21 + tid] = l[20 + tid] * S[1 + p1[tid]] / S[21 + tid];
  __syncthreads();
  if (tid < 250)
    S[91 + tid] = l[90 + tid] * S[21 + p2[tid]] / S[91 + tid];
  __syncthreads();
  if (tid < 800)
    S[341 + tid] = l[340 + tid] * S[91 + p3[tid]] / S[341 + tid];
  __syncthreads();
  for (int s = tid; s < 3000; s += 1024)
    S[1141 + s] = l[1140 + s] * S[341 + p4[s]] / S[1141 + s];
  __syncthreads();

  // ---- Phase 4: p = e * T[parent], coalesced stores ----
  if (tid < 340) {
    if (tid < 20)      out[row * 20 + tid] = l[tid] * S[0];
    else if (tid < 90) out[40960 + row * 70 + (tid - 20)] = l[tid] * S[1 + p1[tid - 20]];
    else               out[184320 + row * 250 + (tid - 90)] = l[tid] * S[21 + p2[tid - 90]];
  }
  if (tid < 200) {
    int4 p = reinterpret_cast<const int4*>(p3)[tid];
    float4 e = reinterpret_cast<const float4*>(l + 340)[tid];
    e.x *= S[91 + p.x]; e.y *= S[91 + p.y]; e.z *= S[91 + p.z]; e.w *= S[91 + p.w];
    reinterpret_cast<float4*>(out + 696320 + row * 800)[tid] = e;
  }
  if (tid < 750) {
    int4 p = reinterpret_cast<const int4*>(p4)[tid];
    float4 e = reinterpret_cast<const float4*>(l + 1140)[tid];
    e.x *= S[341 + p.x]; e.y *= S[341 + p.y]; e.z *= S[341 + p.z]; e.w *= S[341 + p.w];
    reinterpret_cast<float4*>(out + 2334720 + row * 3000)[tid] = e;
  }
  for (int i4 = tid; i4 < 3000; i4 += 1024) {
    int4 p = reinterpret_cast<const int4*>(p5)[i4];
    float4 e = reinterpret_cast<const float4*>(l + 4140)[i4];
    e.x *= S[1141 + p.x]; e.y *= S[1141 + p.y]; e.z *= S[1141 + p.z]; e.w *= S[1141 + p.w];
    reinterpret_cast<float4*>(out + 8478720 + row * 12000)[i4] = e;
  }
}

extern "C" void kernel_launch(void* const* d_in, const int* in_sizes, int n_in,
                              void* d_out, int out_size, void* d_ws, size_t ws_size,
                              hipStream_t stream)
{
  const float* x = (const float*)d_in[0];
  const float* W[6]    = {(const float*)d_in[1], (const float*)d_in[3], (const float*)d_in[5],
                          (const float*)d_in[7], (const float*)d_in[9], (const float*)d_in[11]};
  const float* bias[6] = {(const float*)d_in[2], (const float*)d_in[4], (const float*)d_in[6],
                          (const float*)d_in[8], (const float*)d_in[10], (const float*)d_in[12]};
  const int* p[5] = {(const int*)d_in[13], (const int*)d_in[14], (const int*)d_in[15],
                     (const int*)d_in[16], (const int*)d_in[17]};
  float* out = (float*)d_out;
  char* ws = (char*)d_ws;
  unsigned short* xh = (unsigned short*)ws;                  // 3,145,728 B
  int* gst = (int*)(ws + 27936768);                          // 4142 ints
  float* bcat = (float*)(ws + 27953344);                     // 16140 floats

  // 393216 + 4142 + 16140 = 413498 -> 1616 blocks covers 413,696
  prep_kernel<<<1616, 256, 0, stream>>>(
      x, bias[0], bias[1], bias[2], bias[3], bias[4], bias[5],
      p[0], p[1], p[2], p[3], p[4], xh, gst, bcat);
  gemm_kernel<<<2032, 256, 0, stream>>>(
      xh, W[0], W[1], W[2], W[3], W[4], W[5], out);
  tree_softmax_kernel<<<2048, 1024, 0, stream>>>(
      out, bcat, gst, p[0], p[1], p[2], p[3], p[4]);
}

// Round 8
// 333.022 us; speedup vs baseline: 1.0647x; 1.0647x over previous
//
#include <hip/hip_runtime.h>
#include <stdint.h>

#define BDIM 2048
#define KDIM 768
#define NTOT 16140
#define NKT 24   // 768 / 32

typedef _Float16 half8 __attribute__((ext_vector_type(8)));
typedef float floatx4 __attribute__((ext_vector_type(4)));

__device__ __forceinline__ unsigned short f2h(float f) {
  _Float16 h = (_Float16)f;
  return __builtin_bit_cast(unsigned short, h);
}

__device__ __forceinline__ void level_of(int col, int& cb, int& Cl, long long& ob) {
  if      (col < 20)   { cb = 0;    Cl = 20;    ob = 0LL; }
  else if (col < 90)   { cb = 20;   Cl = 70;    ob = 40960LL; }
  else if (col < 340)  { cb = 90;   Cl = 250;   ob = 184320LL; }
  else if (col < 1140) { cb = 340;  Cl = 800;   ob = 696320LL; }
  else if (col < 4140) { cb = 1140; Cl = 3000;  ob = 2334720LL; }
  else                 { cb = 4140; Cl = 12000; ob = 8478720LL; }
}

// direct global->LDS async copy, 16B per lane; lds dst = uniform base + lane*16
__device__ __forceinline__ void gload_lds16(const void* g, void* l) {
  __builtin_amdgcn_global_load_lds(
      (const __attribute__((address_space(1))) unsigned int*)g,
      (__attribute__((address_space(3))) unsigned int*)l, 16, 0, 0);
}

// ---------------- prep: fp32->fp16 convert (grid-stride, 2-batched) + gst + bcat ----------------
#define PREP_STR 524288LL   // 2048 blocks * 256 threads
#define CONV_N   3492096LL  // (2048*768 + 16140*768)/4 float4 items

__device__ __forceinline__ void conv_addr(
    long long i4, const float* x,
    const float* W0, const float* W1, const float* W2,
    const float* W3, const float* W4, const float* W5,
    unsigned short* xh, unsigned short* wh,
    const float4*& s, ushort4*& d)
{
  long long e = i4 * 4;
  const long long XN = (long long)BDIM * KDIM;  // 1,572,864 floats
  if (e < XN) {
    s = reinterpret_cast<const float4*>(x) + i4;
    d = reinterpret_cast<ushort4*>(xh + e);
  } else {
    long long we = e - XN;
    const float* src; long long off;
    if      (we < 15360)    { src = W0; off = we; }
    else if (we < 69120)    { src = W1; off = we - 15360; }
    else if (we < 261120)   { src = W2; off = we - 69120; }
    else if (we < 875520)   { src = W3; off = we - 261120; }
    else if (we < 3179520)  { src = W4; off = we - 875520; }
    else                    { src = W5; off = we - 3179520; }
    s = reinterpret_cast<const float4*>(src) + (off >> 2);
    d = reinterpret_cast<ushort4*>(wh + we);
  }
}

__device__ __forceinline__ ushort4 cvt4(float4 v) {
  ushort4 o;
  o.x = f2h(v.x); o.y = f2h(v.y); o.z = f2h(v.z); o.w = f2h(v.w);
  return o;
}

__global__ __launch_bounds__(256) void prep_kernel(
    const float* __restrict__ x,
    const float* __restrict__ W0, const float* __restrict__ W1,
    const float* __restrict__ W2, const float* __restrict__ W3,
    const float* __restrict__ W4, const float* __restrict__ W5,
    const float* __restrict__ b0, const float* __restrict__ b1, const float* __restrict__ b2,
    const float* __restrict__ b3, const float* __restrict__ b4, const float* __restrict__ b5,
    const int* __restrict__ p1, const int* __restrict__ p2, const int* __restrict__ p3,
    const int* __restrict__ p4, const int* __restrict__ p5,
    unsigned short* __restrict__ xh, unsigned short* __restrict__ wh,
    int* __restrict__ gst, float* __restrict__ bcat)
{
  const long long gtid = (long long)blockIdx.x * 256 + threadIdx.x;

  // ---- side tables (threads [0, 20282)) ----
  if (gtid < 4142) {
    // gst[j]: child-range start of global parent j in concatenated col space.
    // ids: 0=root; [1,21)=L0; [21,91)=L1; [91,341)=L2; [341,1141)=L3; [1141,4141)=L4.
    int j = (int)gtid;
    int val;
    if (j == 0) val = 0;
    else if (j == 4141) val = 16140;
    else {
      const int* p; int C, s, base;
      if      (j < 21)   { p = p1; C = 70;    s = j - 1;    base = 20; }
      else if (j < 91)   { p = p2; C = 250;   s = j - 21;   base = 90; }
      else if (j < 341)  { p = p3; C = 800;   s = j - 91;   base = 340; }
      else if (j < 1141) { p = p4; C = 3000;  s = j - 341;  base = 1140; }
      else               { p = p5; C = 12000; s = j - 1141; base = 4140; }
      int lo = 0, hi = C;
      while (lo < hi) { int mid = (lo + hi) >> 1; if (p[mid] < s) lo = mid + 1; else hi = mid; }
      val = base + lo;
    }
    gst[j] = val;
  } else if (gtid < 4142 + 16140) {
    int col = (int)(gtid - 4142);
    int cb, Cl; long long ob; level_of(col, cb, Cl, ob);
    const float* bs;
    if      (col < 20)   bs = b0;
    else if (col < 90)   bs = b1;
    else if (col < 340)  bs = b2;
    else if (col < 1140) bs = b3;
    else if (col < 4140) bs = b4;
    else                 bs = b5;
    bcat[col] = bs[col - cb];
  }

  // ---- convert: grid-stride, 2-batched loads for MLP ----
  long long i = gtid;
  while (i + PREP_STR < CONV_N) {
    const float4 *s0, *s1; ushort4 *d0, *d1;
    conv_addr(i,            x, W0, W1, W2, W3, W4, W5, xh, wh, s0, d0);
    conv_addr(i + PREP_STR, x, W0, W1, W2, W3, W4, W5, xh, wh, s1, d1);
    float4 a = *s0;
    float4 b = *s1;
    *d0 = cvt4(a);
    *d1 = cvt4(b);
    i += 2 * PREP_STR;
  }
  if (i < CONV_N) {
    const float4* s0; ushort4* d0;
    conv_addr(i, x, W0, W1, W2, W3, W4, W5, xh, wh, s0, d0);
    *d0 = cvt4(*s0);
  }
}

// ---------------- fp16 MFMA GEMM: logits = x @ Wcat^T ----------------
// m97 structure: global_load_lds width-16 into double-buffered LDS, 1 barrier/K-step.
#define EPI_STRIDE 132 // floats per staged C row (132 mod 32 = 4 -> conflict-free)

__global__ __launch_bounds__(256, 2) void gemm_kernel(
    const unsigned short* __restrict__ Ah,   // [2048][768] fp16
    const unsigned short* __restrict__ Wh,   // [16140][768] fp16
    float* __restrict__ out)
{
  __shared__ __align__(16) char smem_raw[64 * EPI_STRIDE * 4];  // 33792 B; staging uses 32768
  float* epi = (float*)smem_raw;

  // XCD-aware swizzle (2032 = 8*254, bijective)
  const int bid = blockIdx.x;
  const int logical = (bid & 7) * 254 + (bid >> 3);
  const int cx = logical >> 4;                // col tile 0..126
  const int row0 = (logical & 15) * 128;
  const int col0 = cx * 128;

  const int tid  = threadIdx.x;
  const int wave = tid >> 6;
  const int lane = tid & 63;
  const int wr = (wave >> 1) * 64;
  const int wc = (wave & 1) * 64;
  const int q  = lane >> 4;
  const int lr = lane & 15;

  const int rquad = lane >> 2;
  const int kq = lane & 3;

  floatx4 acc[4][4];
#pragma unroll
  for (int i = 0; i < 4; ++i)
#pragma unroll
    for (int j = 0; j < 4; ++j)
      acc[i][j] = (floatx4){0.f, 0.f, 0.f, 0.f};

  const unsigned short* gA[2];
  const unsigned short* gB[2];
#pragma unroll
  for (int i = 0; i < 2; ++i) {
    int c = 2 * wave + i;
    int rowA = row0 + 16 * c + rquad;
    gA[i] = Ah + (long long)rowA * KDIM + kq * 8;
    int colB = col0 + 16 * c + rquad;
    if (colB >= NTOT) colB = NTOT - 1;
    gB[i] = Wh + (long long)colB * KDIM + kq * 8;
  }

  auto stage = [&](int buf, int kt) {
#pragma unroll
    for (int i = 0; i < 2; ++i) {
      int c = 2 * wave + i;
      gload_lds16(gA[i] + kt * 32, smem_raw + buf * 8192 + c * 1024);
      gload_lds16(gB[i] + kt * 32, smem_raw + 16384 + buf * 8192 + c * 1024);
    }
  };

  int cur = 0;
  stage(0, 0);
  __syncthreads();

  for (int kt = 0; kt < NKT; ++kt) {
    if (kt + 1 < NKT) stage(cur ^ 1, kt + 1);
    const char* Ac = smem_raw + cur * 8192;
    const char* Bc = smem_raw + 16384 + cur * 8192;
    half8 af[4], bf[4];
#pragma unroll
    for (int i = 0; i < 4; ++i)
      af[i] = __builtin_bit_cast(half8, *(const uint4*)(Ac + (wr + i * 16 + lr) * 64 + q * 16));
#pragma unroll
    for (int j = 0; j < 4; ++j)
      bf[j] = __builtin_bit_cast(half8, *(const uint4*)(Bc + (wc + j * 16 + lr) * 64 + q * 16));
#pragma unroll
    for (int i = 0; i < 4; ++i)
#pragma unroll
      for (int j = 0; j < 4; ++j)
        acc[i][j] = __builtin_amdgcn_mfma_f32_16x16x32_f16(af[i], bf[j], acc[i][j], 0, 0, 0);
    __syncthreads();
    cur ^= 1;
  }

  // ---- epilogue: stage C-tile through LDS, write coalesced float4 rows ----
  int cbA, ClA; long long obA; level_of(col0, cbA, ClA, obA);
  int cbB, ClB; long long obB; level_of(col0 + 127, cbB, ClB, obB);
  const bool fast = (cbA == cbB) && ((cbA & 3) == 0) && ((ClA & 3) == 0) && (col0 + 128 <= NTOT);

  for (int h = 0; h < 2; ++h) {
    __syncthreads();
    if ((wave >> 1) == h) {
#pragma unroll
      for (int i = 0; i < 4; ++i)
#pragma unroll
        for (int j = 0; j < 4; ++j)
#pragma unroll
          for (int rg = 0; rg < 4; ++rg)
            epi[(i * 16 + q * 4 + rg) * EPI_STRIDE + wc + j * 16 + lr] = acc[i][j][rg];
    }
    __syncthreads();
    if (fast) {
      const long long rowbase = obA + (long long)(row0 + h * 64) * ClA + (col0 - cbA);
#pragma unroll
      for (int it = 0; it < 8; ++it) {
        int idx = it * 256 + tid;
        int r = idx >> 5, f4 = idx & 31;
        float4 v = *(const float4*)(epi + r * EPI_STRIDE + f4 * 4);
        *(float4*)(out + rowbase + (long long)r * ClA + f4 * 4) = v;
      }
    } else {
      for (int idx = tid; idx < 64 * 128; idx += 256) {
        int r = idx >> 7, c = idx & 127;
        int col = col0 + c;
        if (col < NTOT) {
          int cb, Cl; long long ob; level_of(col, cb, Cl, ob);
          out[ob + (long long)(row0 + h * 64 + r) * Cl + (col - cb)] = epi[r * EPI_STRIDE + c];
        }
      }
    }
  }
}

// ---------------- fused 6-level tree softmax, one row per block (1024 thr) ----------------
// p_L[c] = e_L[c] * T[parent(c)],  T[n] = e[n]*T[par(n)]/S[n],  S[n] = sum children e.
// Phase-2 segment sums now 4-way batched: the serial dependent LDS chain (~120cy/elem)
// was the latency hotspot; 4 independent reads/iter cut it ~4x.
__global__ __launch_bounds__(1024) void tree_softmax_kernel(
    float* __restrict__ out,
    const float* __restrict__ bcat, const int* __restrict__ gst,
    const int* __restrict__ p1, const int* __restrict__ p2, const int* __restrict__ p3,
    const int* __restrict__ p4, const int* __restrict__ p5)
{
  __shared__ __align__(16) float l[NTOT];    // e-values, all levels concat
  __shared__ __align__(16) float S[4141];    // seg sums -> T values in place
  const int tid = threadIdx.x;
  const long long row = blockIdx.x;

  // ---- Phase 1: e = exp(logit + bias), one balanced vectorized pass ----
  if (tid < 340) {   // levels 0..2 scalar (20 + 70 + 250)
    float v;
    if      (tid < 20) v = out[row * 20 + tid] + bcat[tid];
    else if (tid < 90) v = out[40960 + row * 70 + (tid - 20)] + bcat[tid];
    else               v = out[184320 + row * 250 + (tid - 90)] + bcat[tid];
    l[tid] = __expf(v);
  }
  if (tid < 200) {   // L3: 800 = 200 float4
    float4 v = reinterpret_cast<const float4*>(out + 696320 + row * 800)[tid];
    float4 b = reinterpret_cast<const float4*>(bcat + 340)[tid];
    float4 e;
    e.x = __expf(v.x + b.x); e.y = __expf(v.y + b.y);
    e.z = __expf(v.z + b.z); e.w = __expf(v.w + b.w);
    reinterpret_cast<float4*>(l + 340)[tid] = e;
  }
  if (tid < 750) {   // L4: 3000 = 750 float4
    float4 v = reinterpret_cast<const float4*>(out + 2334720 + row * 3000)[tid];
    float4 b = reinterpret_cast<const float4*>(bcat + 1140)[tid];
    float4 e;
    e.x = __expf(v.x + b.x); e.y = __expf(v.y + b.y);
    e.z = __expf(v.z + b.z); e.w = __expf(v.w + b.w);
    reinterpret_cast<float4*>(l + 1140)[tid] = e;
  }
  for (int i4 = tid; i4 < 3000; i4 += 1024) { // L5: 12000 = 3000 float4
    float4 v = reinterpret_cast<const float4*>(out + 8478720 + row * 12000)[i4];
    float4 b = reinterpret_cast<const float4*>(bcat + 4140)[i4];
    float4 e;
    e.x = __expf(v.x + b.x); e.y = __expf(v.y + b.y);
    e.z = __expf(v.z + b.z); e.w = __expf(v.w + b.w);
    reinterpret_cast<float4*>(l + 4140)[i4] = e;
  }
  __syncthreads();

  // ---- Phase 2: all segment sums, 4-way batched reads (latency-tolerant) ----
  for (int j = tid; j < 4141; j += 1024) {
    int a = gst[j], b = gst[j + 1];
    float s = 0.f;
    int c = a;
    for (; c + 4 <= b; c += 4) {
      float x0 = l[c], x1 = l[c + 1], x2 = l[c + 2], x3 = l[c + 3];
      s += (x0 + x1) + (x2 + x3);
    }
    for (; c < b; ++c) s += l[c];
    S[j] = s;   // empty segment -> 0 -> T=inf, never gathered
  }
  __syncthreads();

  // ---- Phase 3: T-chain in place over S ----
  if (tid < 20) {            // root + L0 nodes (single wave: S[0] read-before-write safe)
    float s0 = S[0];
    float inv = 1.f / s0;
    float t = l[tid] * inv / S[1 + tid];
    S[1 + tid] = t;
    if (tid == 0) S[0] = inv;
  }
  __syncthreads();
  if (tid < 70)
    S[21 + tid] = l[20 + tid] * S[1 + p1[tid]] / S[21 + tid];
  __syncthreads();
  if (tid < 250)
    S[91 + tid] = l[90 + tid] * S[21 + p2[tid]] / S[91 + tid];
  __syncthreads();
  if (tid < 800)
    S[341 + tid] = l[340 + tid] * S[91 + p3[tid]] / S[341 + tid];
  __syncthreads();
  for (int s = tid; s < 3000; s += 1024)
    S[1141 + s] = l[1140 + s] * S[341 + p4[s]] / S[1141 + s];
  __syncthreads();

  // ---- Phase 4: p = e * T[parent], coalesced stores ----
  if (tid < 340) {
    if (tid < 20)      out[row * 20 + tid] = l[tid] * S[0];
    else if (tid < 90) out[40960 + row * 70 + (tid - 20)] = l[tid] * S[1 + p1[tid - 20]];
    else               out[184320 + row * 250 + (tid - 90)] = l[tid] * S[21 + p2[tid - 90]];
  }
  if (tid < 200) {
    int4 p = reinterpret_cast<const int4*>(p3)[tid];
    float4 e = reinterpret_cast<const float4*>(l + 340)[tid];
    e.x *= S[91 + p.x]; e.y *= S[91 + p.y]; e.z *= S[91 + p.z]; e.w *= S[91 + p.w];
    reinterpret_cast<float4*>(out + 696320 + row * 800)[tid] = e;
  }
  if (tid < 750) {
    int4 p = reinterpret_cast<const int4*>(p4)[tid];
    float4 e = reinterpret_cast<const float4*>(l + 1140)[tid];
    e.x *= S[341 + p.x]; e.y *= S[341 + p.y]; e.z *= S[341 + p.z]; e.w *= S[341 + p.w];
    reinterpret_cast<float4*>(out + 2334720 + row * 3000)[tid] = e;
  }
  for (int i4 = tid; i4 < 3000; i4 += 1024) {
    int4 p = reinterpret_cast<const int4*>(p5)[i4];
    float4 e = reinterpret_cast<const float4*>(l + 4140)[i4];
    e.x *= S[1141 + p.x]; e.y *= S[1141 + p.y]; e.z *= S[1141 + p.z]; e.w *= S[1141 + p.w];
    reinterpret_cast<float4*>(out + 8478720 + row * 12000)[i4] = e;
  }
}

extern "C" void kernel_launch(void* const* d_in, const int* in_sizes, int n_in,
                              void* d_out, int out_size, void* d_ws, size_t ws_size,
                              hipStream_t stream)
{
  const float* x = (const float*)d_in[0];
  const float* W[6]    = {(const float*)d_in[1], (const float*)d_in[3], (const float*)d_in[5],
                          (const float*)d_in[7], (const float*)d_in[9], (const float*)d_in[11]};
  const float* bias[6] = {(const float*)d_in[2], (const float*)d_in[4], (const float*)d_in[6],
                          (const float*)d_in[8], (const float*)d_in[10], (const float*)d_in[12]};
  const int* p[5] = {(const int*)d_in[13], (const int*)d_in[14], (const int*)d_in[15],
                     (const int*)d_in[16], (const int*)d_in[17]};
  float* out = (float*)d_out;
  char* ws = (char*)d_ws;
  unsigned short* xh = (unsigned short*)ws;                  // 3,145,728 B
  unsigned short* wh = (unsigned short*)(ws + 3145728);      // 24,791,040 B
  int* gst = (int*)(ws + 27936768);                          // 4142 ints
  float* bcat = (float*)(ws + 27953344);                     // 16140 floats

  prep_kernel<<<2048, 256, 0, stream>>>(
      x, W[0], W[1], W[2], W[3], W[4], W[5],
      bias[0], bias[1], bias[2], bias[3], bias[4], bias[5],
      p[0], p[1], p[2], p[3], p[4], xh, wh, gst, bcat);
  gemm_kernel<<<2032, 256, 0, stream>>>(xh, wh, out);
  tree_softmax_kernel<<<2048, 1024, 0, stream>>>(
      out, bcat, gst, p[0], p[1], p[2], p[3], p[4]);
}